// Round 4
// baseline (396.886 us; speedup 1.0000x reference)
//
#include <hip/hip_runtime.h>
#include <math.h>
#include <stdint.h>

#define S_TOK 8192
#define M_DIM 4096
#define NEXP 64
#define CAPACITY 256   // K * ceil(S/E) = 2*128
#define NCHUNK 128     // S / 64
#define KS 16          // split-K slices
#define KSL 256        // slice length (KS*KSL = M_DIM)
#define BT 256         // tokens per tile
#define NG (KSL / 4)   // 64 four-k groups per slice

// ---------------------------------------------------------------------------
// K1: partial logits, split-K. Grid 512 = 32 token-tiles x 16 k-slices.
// NO LDS, NO barriers: N=64 is too small for LDS reuse to pay — every 16B
// fragment is consumed by one 8-lane broadcast group of a single wave, and
// global loads broadcast same-address lanes for free through L1.
// 8tok x 8exp register tile; dot-product FMA (B kept k-major, so wg is read
// directly — no transpose kernel). Software-pipelined one 4-k group ahead
// with statically named A0/B0 <-> A1/B1 buffers (rule #20: static indexing).
// ---------------------------------------------------------------------------
__global__ __launch_bounds__(256) void k_logits(
    const float* __restrict__ x, const float* __restrict__ wg,
    float* __restrict__ part)
{
    const int tid = threadIdx.x;
    const int tile = blockIdx.x >> 4;      // 0..31
    const int ks   = blockIdx.x & 15;      // 0..15
    const int t0 = tile * BT;
    const int kb = ks * KSL;

    const int tx = tid & 7;                // experts 8*tx..8*tx+7
    const int ty = tid >> 3;               // tokens  8*ty..8*ty+7

    const float* xrow[8];
    const float* wrow[8];
    #pragma unroll
    for (int i = 0; i < 8; ++i)
        xrow[i] = x + (size_t)(t0 + 8 * ty + i) * M_DIM + kb;
    #pragma unroll
    for (int j = 0; j < 8; ++j)
        wrow[j] = wg + (size_t)(8 * tx + j) * M_DIM + kb;

    float acc[8][8] = {};
    float4 A0[8], B0[8], A1[8], B1[8];

    auto loadg = [&](int g, float4* A, float4* B) {
        #pragma unroll
        for (int i = 0; i < 8; ++i)
            A[i] = *(const float4*)(xrow[i] + 4 * g);
        #pragma unroll
        for (int j = 0; j < 8; ++j)
            B[j] = *(const float4*)(wrow[j] + 4 * g);
    };
    auto fmag = [&](const float4* A, const float4* B) {
        #pragma unroll
        for (int i = 0; i < 8; ++i)
            #pragma unroll
            for (int j = 0; j < 8; ++j) {
                acc[i][j] = fmaf(A[i].x, B[j].x, acc[i][j]);
                acc[i][j] = fmaf(A[i].y, B[j].y, acc[i][j]);
                acc[i][j] = fmaf(A[i].z, B[j].z, acc[i][j]);
                acc[i][j] = fmaf(A[i].w, B[j].w, acc[i][j]);
            }
    };

    loadg(0, A0, B0);
    for (int g = 0; g < NG - 2; g += 2) {
        loadg(g + 1, A1, B1);
        fmag(A0, B0);
        loadg(g + 2, A0, B0);
        fmag(A1, B1);
    }
    // g == NG-2
    loadg(NG - 1, A1, B1);
    fmag(A0, B0);
    fmag(A1, B1);

    #pragma unroll
    for (int i = 0; i < 8; ++i) {
        float4 v0, v1;
        v0.x = acc[i][0]; v0.y = acc[i][1]; v0.z = acc[i][2]; v0.w = acc[i][3];
        v1.x = acc[i][4]; v1.y = acc[i][5]; v1.z = acc[i][6]; v1.w = acc[i][7];
        float* dst = part + ((size_t)ks * S_TOK + t0 + 8 * ty + i) * NEXP + 8 * tx;
        *(float4*)dst = v0;
        *(float4*)(dst + 4) = v1;
    }
}

// ---------------------------------------------------------------------------
// K2 (fused reduce+rank): 64 tokens per block (8 waves x 8 tokens).
// Reduce partials (deterministic slice order) + softmax + top-2 + me,
// then wave 0 does the per-chunk in-order ranks/histograms via ballots.
// ---------------------------------------------------------------------------
__global__ __launch_bounds__(512) void k_gate(
    const float* __restrict__ part, float* __restrict__ me_g,
    int* __restrict__ idx0_g, int* __restrict__ idx1_g,
    float* __restrict__ gn0_g, float* __restrict__ gn1_g,
    int* __restrict__ rank0_g, int* __restrict__ rank1_g,
    int* __restrict__ cnt_g /* [2][NCHUNK][64] */)
{
    __shared__ float me_sh[NEXP];
    __shared__ int e0_sh[64], e1_sh[64];
    const int tid = threadIdx.x;
    if (tid < NEXP) me_sh[tid] = 0.f;
    __syncthreads();

    const int wv = tid >> 6, lane = tid & 63;
    const int chunk = blockIdx.x;
    float me_acc = 0.f;
    for (int i = 0; i < 8; ++i) {
        const int tt = wv * 8 + i;
        const int t = chunk * 64 + tt;
        float lg = 0.f;
        #pragma unroll
        for (int s = 0; s < KS; ++s)
            lg += part[((size_t)s * S_TOK + t) * NEXP + lane];

        // argmax (lowest index on tie, matching lax.top_k)
        float v = lg; int id = lane;
        #pragma unroll
        for (int off = 32; off > 0; off >>= 1) {
            float v2 = __shfl_xor(v, off);
            int   i2 = __shfl_xor(id, off);
            if (v2 > v || (v2 == v && i2 < id)) { v = v2; id = i2; }
        }
        const float mx = v; const int i0 = id;

        const float p = expf(lg - mx);
        float sum = p;
        #pragma unroll
        for (int off = 32; off > 0; off >>= 1) sum += __shfl_xor(sum, off);
        me_acc += p / sum;

        // second argmax, excluding i0
        float v1 = (lane == i0) ? -INFINITY : lg; int id1 = lane;
        #pragma unroll
        for (int off = 32; off > 0; off >>= 1) {
            float v2 = __shfl_xor(v1, off);
            int   i2 = __shfl_xor(id1, off);
            if (v2 > v1 || (v2 == v1 && i2 < id1)) { v1 = v2; id1 = i2; }
        }

        const float g0 = 1.0f / sum;
        const float g1 = expf(v1 - mx) / sum;
        const float den = fmaxf(g0 + g1, 1.1920929e-07f);
        if (lane == 0) {
            idx0_g[t] = i0;
            idx1_g[t] = id1;
            gn0_g[t] = g0 / den;
            gn1_g[t] = g1 / den;
            e0_sh[tt] = i0;
            e1_sh[tt] = id1;
        }
    }
    atomicAdd(&me_sh[lane], me_acc);
    __syncthreads();
    if (tid < NEXP) atomicAdd(&me_g[tid], me_sh[tid]);

    // rank phase: wave 0, lane = token within chunk
    if (wv == 0) {
        const int s = chunk * 64 + lane;
        const int e0 = e0_sh[lane], e1 = e1_sh[lane];
        const unsigned long long lt = (1ull << lane) - 1ull;
        int r0 = 0, r1 = 0, c0 = 0, c1 = 0;
        #pragma unroll
        for (int e = 0; e < 64; ++e) {
            unsigned long long m0 = __ballot(e0 == e);
            unsigned long long m1 = __ballot(e1 == e);
            if (e0 == e) r0 = __popcll(m0 & lt);
            if (e1 == e) r1 = __popcll(m1 & lt);
            if (lane == e) { c0 = __popcll(m0); c1 = __popcll(m1); }
        }
        rank0_g[s] = r0;
        rank1_g[s] = r1;
        cnt_g[chunk * 64 + lane] = c0;
        cnt_g[NCHUNK * 64 + chunk * 64 + lane] = c1;
    }
}

// ---------------------------------------------------------------------------
// K3: parallel scan — one wave per (k,e), shfl prefix over 128 chunks.
// Also emits ce (tot0) and the load-balance loss.
// ---------------------------------------------------------------------------
__global__ __launch_bounds__(256) void k_scan(
    const int* __restrict__ cnt_g, int* __restrict__ base_g,
    int* __restrict__ tot0_g, const float* __restrict__ me_g,
    float* __restrict__ loss_out)
{
    const int wv = threadIdx.x >> 6, lane = threadIdx.x & 63;
    const int g = blockIdx.x * 4 + wv;         // 0..127
    const int k = g >> 6, e = g & 63;

    const int c0 = cnt_g[(k * NCHUNK + 2 * lane)     * 64 + e];
    const int c1 = cnt_g[(k * NCHUNK + 2 * lane + 1) * 64 + e];
    const int s = c0 + c1;
    int incl = s;
    #pragma unroll
    for (int d = 1; d < 64; d <<= 1) {
        int v = __shfl_up(incl, d);
        if (lane >= d) incl += v;
    }
    const int excl = incl - s;
    base_g[(k * NCHUNK + 2 * lane)     * 64 + e] = excl;
    base_g[(k * NCHUNK + 2 * lane + 1) * 64 + e] = excl + c0;
    const int total = __shfl(incl, 63);
    if (k == 0 && lane == 0) {
        tot0_g[e] = total;
        atomicAdd(loss_out, me_g[e] * (float)total * 9.5367431640625e-07f); // E/S^2
    }
}

// ---------------------------------------------------------------------------
// K4 (fused weight+out): per-token combine weight (capacity check) computed
// block-uniformly (L1 broadcast loads), then out[s,:] = w * x[s,:].
// ---------------------------------------------------------------------------
__global__ __launch_bounds__(256) void k_out(
    const float* __restrict__ x,
    const int* __restrict__ idx0_g, const int* __restrict__ idx1_g,
    const float* __restrict__ gn0_g, const float* __restrict__ gn1_g,
    const int* __restrict__ rank0_g, const int* __restrict__ rank1_g,
    const int* __restrict__ base_g, const int* __restrict__ tot0_g,
    float* __restrict__ out)
{
    const int s = blockIdx.x;
    const int chunk = s >> 6;
    const int e0 = idx0_g[s], e1 = idx1_g[s];
    const int loc0 = base_g[chunk * 64 + e0] + rank0_g[s];
    const int loc1 = base_g[(NCHUNK + chunk) * 64 + e1] + rank1_g[s] + tot0_g[e1];
    float w = 0.f;
    if (loc0 < CAPACITY) w += gn0_g[s];
    if (loc1 < CAPACITY) w += gn1_g[s];

    const float4* xr = (const float4*)(x + (size_t)s * M_DIM);
    float4* o = (float4*)(out + (size_t)s * M_DIM);
    #pragma unroll
    for (int i = 0; i < 4; ++i) {
        float4 v = xr[threadIdx.x + 256 * i];
        v.x *= w; v.y *= w; v.z *= w; v.w *= w;
        o[threadIdx.x + 256 * i] = v;
    }
}

// ---------------------------------------------------------------------------
extern "C" void kernel_launch(void* const* d_in, const int* in_sizes, int n_in,
                              void* d_out, int out_size, void* d_ws, size_t ws_size,
                              hipStream_t stream)
{
    const float* x  = (const float*)d_in[0];
    const float* wg = (const float*)d_in[1];
    float* out = (float*)d_out;
    float* loss = out + (size_t)S_TOK * M_DIM;

    // ws layout (floats/ints, 4B):
    float* part = (float*)d_ws;                         // [KS][S][E] = 33.55 MB
    float* me   = part + (size_t)KS * S_TOK * NEXP;     // [64]
    int*  idx0  = (int*)(me + NEXP);                    // [S]
    int*  idx1  = idx0 + S_TOK;                         // [S]
    float* gn0  = (float*)(idx1 + S_TOK);               // [S]
    float* gn1  = gn0 + S_TOK;                          // [S]
    int*  rank0 = (int*)(gn1 + S_TOK);                  // [S]
    int*  rank1 = rank0 + S_TOK;                        // [S]
    int*  cnt   = rank1 + S_TOK;                        // [2][128][64]
    int*  base  = cnt + 2 * NCHUNK * 64;                // [2][128][64]
    int*  tot0  = base + 2 * NCHUNK * 64;               // [64]

    hipMemsetAsync(me, 0, NEXP * sizeof(float), stream);
    hipMemsetAsync(loss, 0, sizeof(float), stream);

    k_logits<<<32 * KS, 256, 0, stream>>>(x, wg, part);
    k_gate<<<NCHUNK, 512, 0, stream>>>(part, me, idx0, idx1, gn0, gn1,
                                       rank0, rank1, cnt);
    k_scan<<<32, 256, 0, stream>>>(cnt, base, tot0, me, loss);
    k_out<<<S_TOK, 256, 0, stream>>>(x, idx0, idx1, gn0, gn1,
                                     rank0, rank1, base, tot0, out);
}

// Round 6
// 324.231 us; speedup vs baseline: 1.2241x; 1.2241x over previous
//
#include <hip/hip_runtime.h>
#include <math.h>
#include <stdint.h>

#define S_TOK 8192
#define M_DIM 4096
#define NEXP 64
#define CAPACITY 256   // K * ceil(S/E) = 2*128
#define NCHUNK 128     // S / 64
#define KS 16          // split-K slices
#define KSL 256        // slice length (KS*KSL = M_DIM)
#define BT 128         // tokens per tile
#define BK 32          // k per LDS chunk
#define NC (KSL / BK)  // 8 chunks per slice

// ---------------------------------------------------------------------------
// K0: transpose gate weight once: wgT[k][e] = wg[e][k]  (1 MB).
// Gives k_logits a k-major row so B can be fetched as s_load_dwordx16.
// ---------------------------------------------------------------------------
__global__ __launch_bounds__(256) void k_wt(
    const float* __restrict__ wg, float* __restrict__ wgT)
{
    const int k = blockIdx.x * 4 + (threadIdx.x >> 6);
    const int e = threadIdx.x & 63;
    wgT[(size_t)k * NEXP + e] = wg[(size_t)e * M_DIM + k];
}

// ---------------------------------------------------------------------------
// K1: partial logits, split-K. Grid 1024 = 64 token-tiles x 16 k-slices.
// KEY: B (gate weights) is wave-uniform per k -> lives in SGPRs via uniform-
// address loads (readfirstlane'd wave id, blockIdx/loop-uniform k). The FMA
// reads the SGPR operand directly (v_fmac v,s,v) — ZERO per-thread B-load
// instructions on the LDS/VMEM pipes (v0-v3 all paid for B per wave).
// A: lane = token; LDS tile [128 tok][32 k] staged via global_load_lds w16
// (linear dest, source k-quad XOR-swizzled by tok&7 per m173); each lane
// reads its OWN token's float4 -> 1 ds_read_b128 per 128 FMAs (8x less LDS
// pipe than v1; ~8-way conflict on that rare read is immaterial).
// Wave = 64 tokens x 32 experts (acc[32]); block = 2 tok-groups x 2 e-groups.
// One barrier per chunk, stage(next) issued before compute(cur).
// ---------------------------------------------------------------------------
__global__ __launch_bounds__(256) void k_logits(
    const float* __restrict__ x, const float* __restrict__ wgT,
    float* __restrict__ part)
{
    __shared__ float xs[2][BT * BK];   // 16 KB per buffer
    const int tid = threadIdx.x;
    const int tile = blockIdx.x >> 4;      // 0..63
    const int ks   = blockIdx.x & 15;      // 0..15
    const int t0 = tile * BT;
    const int kb = ks * KSL;

    const int lane = tid & 63;
    const int wv = __builtin_amdgcn_readfirstlane(tid >> 6);  // uniform
    const int tg = wv >> 1;                // token group 0/1
    const int eg = wv & 1;                 // expert group 0/1
    const int tok_l = tg * 64 + lane;      // this lane's token within tile

    auto stage = [&](int buf, int kc) {
        #pragma unroll
        for (int i = 0; i < 4; ++i) {
            const int item = tid + 256 * i;        // 1024 items x 16B = 16 KB
            const int tok = item >> 3;             // 0..127
            const int kqp = item & 7;              // phys k-quad slot
            const int kqs = kqp ^ (tok & 7);       // source k-quad (swizzle)
            __builtin_amdgcn_global_load_lds(
                (const __attribute__((address_space(1))) void*)
                    (x + (size_t)(t0 + tok) * M_DIM + kc + 4 * kqs),
                (__attribute__((address_space(3))) void*)(&xs[buf][item * 4]),
                16, 0, 0);
        }
    };

    float acc[32] = {};
    stage(0, kb);
    __syncthreads();

    for (int c = 0; c < NC; ++c) {
        const int buf = c & 1;
        const int kc = kb + c * BK;
        if (c + 1 < NC) stage(buf ^ 1, kc + BK);

        #pragma unroll
        for (int kq = 0; kq < 8; ++kq) {
            const float4 a = *(const float4*)
                &xs[buf][tok_l * BK + ((kq ^ (lane & 7)) << 2)];
            const float av[4] = {a.x, a.y, a.z, a.w};
            #pragma unroll
            for (int kk = 0; kk < 4; ++kk) {
                // uniform address -> s_load (SGPR B operand)
                const float* brow =
                    wgT + (size_t)(kc + 4 * kq + kk) * NEXP + eg * 32;
                #pragma unroll
                for (int e = 0; e < 32; ++e)
                    acc[e] = fmaf(brow[e], av[kk], acc[e]);
            }
        }
        __syncthreads();
    }

    // store: part[ks][t0+tok_l][eg*32 .. +32)
    float* dst = part + ((size_t)ks * S_TOK + t0 + tok_l) * NEXP + eg * 32;
    #pragma unroll
    for (int q = 0; q < 8; ++q) {
        float4 v;
        v.x = acc[4 * q];     v.y = acc[4 * q + 1];
        v.z = acc[4 * q + 2]; v.w = acc[4 * q + 3];
        *(float4*)(dst + 4 * q) = v;
    }
}

// ---------------------------------------------------------------------------
// K2 (fused reduce+rank): 64 tokens per block (8 waves x 8 tokens).
// Reduce partials (deterministic slice order) + softmax + top-2 + me,
// then wave 0 does the per-chunk in-order ranks/histograms via ballots.
// ---------------------------------------------------------------------------
__global__ __launch_bounds__(512) void k_gate(
    const float* __restrict__ part, float* __restrict__ me_g,
    int* __restrict__ idx0_g, int* __restrict__ idx1_g,
    float* __restrict__ gn0_g, float* __restrict__ gn1_g,
    int* __restrict__ rank0_g, int* __restrict__ rank1_g,
    int* __restrict__ cnt_g /* [2][NCHUNK][64] */)
{
    __shared__ float me_sh[NEXP];
    __shared__ int e0_sh[64], e1_sh[64];
    const int tid = threadIdx.x;
    if (tid < NEXP) me_sh[tid] = 0.f;
    __syncthreads();

    const int wv = tid >> 6, lane = tid & 63;
    const int chunk = blockIdx.x;
    float me_acc = 0.f;
    for (int i = 0; i < 8; ++i) {
        const int tt = wv * 8 + i;
        const int t = chunk * 64 + tt;
        float lg = 0.f;
        #pragma unroll
        for (int s = 0; s < KS; ++s)
            lg += part[((size_t)s * S_TOK + t) * NEXP + lane];

        // argmax (lowest index on tie, matching lax.top_k)
        float v = lg; int id = lane;
        #pragma unroll
        for (int off = 32; off > 0; off >>= 1) {
            float v2 = __shfl_xor(v, off);
            int   i2 = __shfl_xor(id, off);
            if (v2 > v || (v2 == v && i2 < id)) { v = v2; id = i2; }
        }
        const float mx = v; const int i0 = id;

        const float p = expf(lg - mx);
        float sum = p;
        #pragma unroll
        for (int off = 32; off > 0; off >>= 1) sum += __shfl_xor(sum, off);
        me_acc += p / sum;

        // second argmax, excluding i0
        float v1 = (lane == i0) ? -INFINITY : lg; int id1 = lane;
        #pragma unroll
        for (int off = 32; off > 0; off >>= 1) {
            float v2 = __shfl_xor(v1, off);
            int   i2 = __shfl_xor(id1, off);
            if (v2 > v1 || (v2 == v1 && i2 < id1)) { v1 = v2; id1 = i2; }
        }

        const float g0 = 1.0f / sum;
        const float g1 = expf(v1 - mx) / sum;
        const float den = fmaxf(g0 + g1, 1.1920929e-07f);
        if (lane == 0) {
            idx0_g[t] = i0;
            idx1_g[t] = id1;
            gn0_g[t] = g0 / den;
            gn1_g[t] = g1 / den;
            e0_sh[tt] = i0;
            e1_sh[tt] = id1;
        }
    }
    atomicAdd(&me_sh[lane], me_acc);
    __syncthreads();
    if (tid < NEXP) atomicAdd(&me_g[tid], me_sh[tid]);

    // rank phase: wave 0, lane = token within chunk
    if (wv == 0) {
        const int s = chunk * 64 + lane;
        const int e0 = e0_sh[lane], e1 = e1_sh[lane];
        const unsigned long long lt = (1ull << lane) - 1ull;
        int r0 = 0, r1 = 0, c0 = 0, c1 = 0;
        #pragma unroll
        for (int e = 0; e < 64; ++e) {
            unsigned long long m0 = __ballot(e0 == e);
            unsigned long long m1 = __ballot(e1 == e);
            if (e0 == e) r0 = __popcll(m0 & lt);
            if (e1 == e) r1 = __popcll(m1 & lt);
            if (lane == e) { c0 = __popcll(m0); c1 = __popcll(m1); }
        }
        rank0_g[s] = r0;
        rank1_g[s] = r1;
        cnt_g[chunk * 64 + lane] = c0;
        cnt_g[NCHUNK * 64 + chunk * 64 + lane] = c1;
    }
}

// ---------------------------------------------------------------------------
// K3: parallel scan — one wave per (k,e), shfl prefix over 128 chunks.
// Also emits ce (tot0) and the load-balance loss.
// ---------------------------------------------------------------------------
__global__ __launch_bounds__(256) void k_scan(
    const int* __restrict__ cnt_g, int* __restrict__ base_g,
    int* __restrict__ tot0_g, const float* __restrict__ me_g,
    float* __restrict__ loss_out)
{
    const int wv = threadIdx.x >> 6, lane = threadIdx.x & 63;
    const int g = blockIdx.x * 4 + wv;         // 0..127
    const int k = g >> 6, e = g & 63;

    const int c0 = cnt_g[(k * NCHUNK + 2 * lane)     * 64 + e];
    const int c1 = cnt_g[(k * NCHUNK + 2 * lane + 1) * 64 + e];
    const int s = c0 + c1;
    int incl = s;
    #pragma unroll
    for (int d = 1; d < 64; d <<= 1) {
        int v = __shfl_up(incl, d);
        if (lane >= d) incl += v;
    }
    const int excl = incl - s;
    base_g[(k * NCHUNK + 2 * lane)     * 64 + e] = excl;
    base_g[(k * NCHUNK + 2 * lane + 1) * 64 + e] = excl + c0;
    const int total = __shfl(incl, 63);
    if (k == 0 && lane == 0) {
        tot0_g[e] = total;
        atomicAdd(loss_out, me_g[e] * (float)total * 9.5367431640625e-07f); // E/S^2
    }
}

// ---------------------------------------------------------------------------
// K4 (fused weight+out): per-token combine weight (capacity check) computed
// block-uniformly (L1 broadcast loads), then out[s,:] = w * x[s,:].
// ---------------------------------------------------------------------------
__global__ __launch_bounds__(256) void k_out(
    const float* __restrict__ x,
    const int* __restrict__ idx0_g, const int* __restrict__ idx1_g,
    const float* __restrict__ gn0_g, const float* __restrict__ gn1_g,
    const int* __restrict__ rank0_g, const int* __restrict__ rank1_g,
    const int* __restrict__ base_g, const int* __restrict__ tot0_g,
    float* __restrict__ out)
{
    const int s = blockIdx.x;
    const int chunk = s >> 6;
    const int e0 = idx0_g[s], e1 = idx1_g[s];
    const int loc0 = base_g[chunk * 64 + e0] + rank0_g[s];
    const int loc1 = base_g[(NCHUNK + chunk) * 64 + e1] + rank1_g[s] + tot0_g[e1];
    float w = 0.f;
    if (loc0 < CAPACITY) w += gn0_g[s];
    if (loc1 < CAPACITY) w += gn1_g[s];

    const float4* xr = (const float4*)(x + (size_t)s * M_DIM);
    float4* o = (float4*)(out + (size_t)s * M_DIM);
    #pragma unroll
    for (int i = 0; i < 4; ++i) {
        float4 v = xr[threadIdx.x + 256 * i];
        v.x *= w; v.y *= w; v.z *= w; v.w *= w;
        o[threadIdx.x + 256 * i] = v;
    }
}

// ---------------------------------------------------------------------------
extern "C" void kernel_launch(void* const* d_in, const int* in_sizes, int n_in,
                              void* d_out, int out_size, void* d_ws, size_t ws_size,
                              hipStream_t stream)
{
    const float* x  = (const float*)d_in[0];
    const float* wg = (const float*)d_in[1];
    float* out = (float*)d_out;
    float* loss = out + (size_t)S_TOK * M_DIM;

    // ws layout (floats/ints, 4B):
    float* part = (float*)d_ws;                         // [KS][S][E] = 33.55 MB
    float* me   = part + (size_t)KS * S_TOK * NEXP;     // [64]
    int*  idx0  = (int*)(me + NEXP);                    // [S]
    int*  idx1  = idx0 + S_TOK;                         // [S]
    float* gn0  = (float*)(idx1 + S_TOK);               // [S]
    float* gn1  = gn0 + S_TOK;                          // [S]
    int*  rank0 = (int*)(gn1 + S_TOK);                  // [S]
    int*  rank1 = rank0 + S_TOK;                        // [S]
    int*  cnt   = rank1 + S_TOK;                        // [2][128][64]
    int*  base  = cnt + 2 * NCHUNK * 64;                // [2][128][64]
    int*  tot0  = base + 2 * NCHUNK * 64;               // [64]
    float* wgT  = (float*)(tot0 + NEXP);                // [M][E] = 1 MB

    hipMemsetAsync(me, 0, NEXP * sizeof(float), stream);
    hipMemsetAsync(loss, 0, sizeof(float), stream);

    k_wt<<<M_DIM / 4, 256, 0, stream>>>(wg, wgT);
    k_logits<<<(S_TOK / BT) * KS, 256, 0, stream>>>(x, wgT, part);
    k_gate<<<NCHUNK, 512, 0, stream>>>(part, me, idx0, idx1, gn0, gn1,
                                       rank0, rank1, cnt);
    k_scan<<<32, 256, 0, stream>>>(cnt, base, tot0, me, loss);
    k_out<<<S_TOK, 256, 0, stream>>>(x, idx0, idx1, gn0, gn1,
                                     rank0, rank1, base, tot0, out);
}